// Round 6
// baseline (136.376 us; speedup 1.0000x reference)
//
#include <hip/hip_runtime.h>
#include <hip/hip_bf16.h>

#define NN 8192
#define INF_ 256
#define OUTF 64
#define ALPHA 0.2f

typedef __attribute__((ext_vector_type(8))) short short8;
typedef __attribute__((ext_vector_type(4))) float f32x4;

static __device__ __forceinline__ unsigned short f2bf(float f) {
  unsigned u = __builtin_bit_cast(unsigned, f);
  u += 0x7fffu + ((u >> 16) & 1u);          // RNE; inputs are finite
  return (unsigned short)(u >> 16);
}

// ---------------- Kernel A: h' = X@W -> hptF (bf16, MFMA B-fragment order), s1, s2, block s2max
// hptF[((t*4+s)*64 + lane)*8 + j] = h'[t*32 + (lane>>4)*8 + j][s*16 + (lane&15)]
__global__ __launch_bounds__(256) void k_prep(
    const float* __restrict__ X, const float* __restrict__ W,
    const float* __restrict__ a1, const float* __restrict__ a2,
    unsigned short* __restrict__ hptF, float* __restrict__ s1,
    float* __restrict__ s2, float* __restrict__ pmax)
{
  __shared__ float Ws[INF_ * OUTF];   // 64 KB
  __shared__ float Xs[32 * INF_];     // 32 KB
  __shared__ float sm8[8];
  const int t = threadIdx.x;
  const int ib = blockIdx.x;

  #pragma unroll
  for (int i = 0; i < 16; ++i) {
    const int idx = (i * 256 + t) * 4;
    *reinterpret_cast<float4*>(&Ws[idx]) = *reinterpret_cast<const float4*>(&W[idx]);
  }
  const float* Xb = X + (size_t)ib * 32 * INF_;
  #pragma unroll
  for (int i = 0; i < 8; ++i) {
    const int idx = (i * 256 + t) * 4;
    *reinterpret_cast<float4*>(&Xs[idx]) = *reinterpret_cast<const float4*>(&Xb[idx]);
  }
  __syncthreads();

  const int rg = t >> 5;          // 0..7 -> nodes 4*rg..4*rg+3
  const int r0 = rg * 4;
  const int c0 = 2 * (t & 31);    // 2 consecutive output features
  float acc[4][2] = {{0.f,0.f},{0.f,0.f},{0.f,0.f},{0.f,0.f}};

  for (int k = 0; k < INF_; k += 4) {
    float xv[4][4];
    #pragma unroll
    for (int rr = 0; rr < 4; ++rr)
      *reinterpret_cast<float4*>(&xv[rr][0]) =
          *reinterpret_cast<const float4*>(&Xs[(r0 + rr) * INF_ + k]);
    #pragma unroll
    for (int kk = 0; kk < 4; ++kk) {
      const float2 wv = *reinterpret_cast<const float2*>(&Ws[(k + kk) * OUTF + c0]);
      #pragma unroll
      for (int rr = 0; rr < 4; ++rr) {
        acc[rr][0] = fmaf(xv[rr][kk], wv.x, acc[rr][0]);
        acc[rr][1] = fmaf(xv[rr][kk], wv.y, acc[rr][1]);
      }
    }
  }

  const float a10 = a1[c0], a11 = a1[c0 + 1];
  const float a20 = a2[c0], a21 = a2[c0 + 1];
  float sp1[4], sp2[4];
  #pragma unroll
  for (int rr = 0; rr < 4; ++rr) {
    sp1[rr] = acc[rr][0] * a10 + acc[rr][1] * a11;
    sp2[rr] = acc[rr][0] * a20 + acc[rr][1] * a21;
  }
  #pragma unroll
  for (int d = 1; d < 32; d <<= 1) {
    #pragma unroll
    for (int rr = 0; rr < 4; ++rr) {
      sp1[rr] += __shfl_xor(sp1[rr], d, 64);
      sp2[rr] += __shfl_xor(sp2[rr], d, 64);
    }
  }

  // fragment-order store
  const int jj0 = (rg & 1) * 4;
  const int lhi = rg >> 1;
  #pragma unroll
  for (int cc = 0; cc < 2; ++cc) {
    const int feat = c0 + cc;
    const int s = feat >> 4;
    const int ln = lhi * 16 + (feat & 15);
    ushort4 pk;
    pk.x = f2bf(acc[0][cc]); pk.y = f2bf(acc[1][cc]);
    pk.z = f2bf(acc[2][cc]); pk.w = f2bf(acc[3][cc]);
    *reinterpret_cast<ushort4*>(&hptF[(size_t)ib * 2048 + s * 512 + ln * 8 + jj0]) = pk;
  }
  const int gr = ib * 32 + r0;
  if ((t & 31) == 0) {
    #pragma unroll
    for (int rr = 0; rr < 4; ++rr) { s1[gr + rr] = sp1[rr]; s2[gr + rr] = sp2[rr]; }
    sm8[rg] = fmaxf(fmaxf(sp2[0], sp2[1]), fmaxf(sp2[2], sp2[3]));
  }
  __syncthreads();
  if (t == 0) {
    float m = sm8[0];
    #pragma unroll
    for (int i = 1; i < 8; ++i) m = fmaxf(m, sm8[i]);
    pmax[ib] = m;
  }
}

// ---------------- Kernel E: global s2-max + factor tables.
// exp(lrelu(s1_i+s2_j) - m_i) == (E2_j >= TR_i i.e. s1_i+s2_j>=0) ? E1_i*E2_j : F1_i*F2_j.
__global__ __launch_bounds__(256) void k_ef(
    const float* __restrict__ s1, const float* __restrict__ s2,
    const float* __restrict__ pmax, float* __restrict__ ef2, float4* __restrict__ rowp)
{
  __shared__ float smx[4];
  const int t = threadIdx.x;
  float m = pmax[t];
  #pragma unroll
  for (int d = 1; d < 64; d <<= 1) m = fmaxf(m, __shfl_xor(m, d, 64));
  if ((t & 63) == 0) smx[t >> 6] = m;
  __syncthreads();
  const float S2M = fmaxf(fmaxf(smx[0], smx[1]), fmaxf(smx[2], smx[3]));

  const int i = blockIdx.x * 256 + t;      // 8192
  const float d = s2[i] - S2M;
  ef2[2 * i]     = expf(d);                // E2 <= 1
  ef2[2 * i + 1] = expf(ALPHA * d);        // F2 <= 1
  const float y = s1[i] + S2M;             // m_i = lrelu(y)
  const float e1 = y >= 0.f ? 1.f : expf((1.f - ALPHA) * y);
  const float f1 = y >= 0.f ? expf(-(1.f - ALPHA) * y) : 1.f;
  const float tr = expf(-y);               // E2_j >= TR_i  <=>  s1_i+s2_j >= 0
  rowp[i] = make_float4(e1, f1, tr, 0.f);
}

// ---------------- Kernel C: fused masked-softmax numerator + attn@h' partials.
// grid 1024 = 16 K-chunks x 64 row-groups; 512 thr. Block = 128 rows x 512 cols.
// h' fragments (64KB) + ef table (4KB) staged in LDS once (8x wave reuse) -> in-loop
// VMEM is ONLY the adj stream, so vmcnt counts adj alone (decoupled from lgkmcnt)
// and the depth-1-iter register prefetch gets a full iteration of hiding.
// Partials combined across K-chunk blocks via f32 atomicAdd into zeroed accb/den.
#define KSBODY(TGL, A4, B4)                                                      \
  {                                                                              \
    const unsigned short* bp = &hpS[(TGL) * 2048 + (lane << 3)];                 \
    const short8 b0 = *reinterpret_cast<const short8*>(bp);                      \
    const short8 b1 = *reinterpret_cast<const short8*>(bp + 512);                \
    const short8 b2 = *reinterpret_cast<const short8*>(bp + 1024);               \
    const short8 b3 = *reinterpret_cast<const short8*>(bp + 1536);               \
    const float* ep = &efS[((TGL) * 32 + (kq << 3)) * 2];                        \
    const float4 eA = *reinterpret_cast<const float4*>(ep);                      \
    const float4 eB = *reinterpret_cast<const float4*>(ep + 4);                  \
    const float4 eC = *reinterpret_cast<const float4*>(ep + 8);                  \
    const float4 eD = *reinterpret_cast<const float4*>(ep + 12);                 \
    const float p0 = ((A4).x > 0) ? ((eA.x >= TR) ? E1 * eA.x : F1 * eA.y) : 0.f;\
    const float p1 = ((A4).y > 0) ? ((eA.z >= TR) ? E1 * eA.z : F1 * eA.w) : 0.f;\
    const float p2 = ((A4).z > 0) ? ((eB.x >= TR) ? E1 * eB.x : F1 * eB.y) : 0.f;\
    const float p3 = ((A4).w > 0) ? ((eB.z >= TR) ? E1 * eB.z : F1 * eB.w) : 0.f;\
    const float p4 = ((B4).x > 0) ? ((eC.x >= TR) ? E1 * eC.x : F1 * eC.y) : 0.f;\
    const float p5 = ((B4).y > 0) ? ((eC.z >= TR) ? E1 * eC.z : F1 * eC.w) : 0.f;\
    const float p6 = ((B4).z > 0) ? ((eD.x >= TR) ? E1 * eD.x : F1 * eD.y) : 0.f;\
    const float p7 = ((B4).w > 0) ? ((eD.z >= TR) ? E1 * eD.z : F1 * eD.w) : 0.f;\
    lpart += ((p0 + p1) + (p2 + p3)) + ((p4 + p5) + (p6 + p7));                  \
    unsigned q0, q1, q2, q3;                                                     \
    asm("v_cvt_pk_bf16_f32 %0, %1, %2" : "=v"(q0) : "v"(p0), "v"(p1));           \
    asm("v_cvt_pk_bf16_f32 %0, %1, %2" : "=v"(q1) : "v"(p2), "v"(p3));           \
    asm("v_cvt_pk_bf16_f32 %0, %1, %2" : "=v"(q2) : "v"(p4), "v"(p5));           \
    asm("v_cvt_pk_bf16_f32 %0, %1, %2" : "=v"(q3) : "v"(p6), "v"(p7));           \
    union { unsigned u[4]; short8 s8; } cv;                                      \
    cv.u[0] = q0; cv.u[1] = q1; cv.u[2] = q2; cv.u[3] = q3;                      \
    const short8 af = cv.s8;                                                     \
    acc0 = __builtin_amdgcn_mfma_f32_16x16x32_bf16(af, b0, acc0, 0, 0, 0);       \
    acc1 = __builtin_amdgcn_mfma_f32_16x16x32_bf16(af, b1, acc1, 0, 0, 0);       \
    acc2 = __builtin_amdgcn_mfma_f32_16x16x32_bf16(af, b2, acc2, 0, 0, 0);       \
    acc3 = __builtin_amdgcn_mfma_f32_16x16x32_bf16(af, b3, acc3, 0, 0, 0);       \
  }

__global__ __launch_bounds__(512, 4) void k_main2(
    const int* __restrict__ adj, const unsigned short* __restrict__ hptF,
    const float* __restrict__ ef2, const float4* __restrict__ rowp,
    float* __restrict__ accb, float* __restrict__ den)
{
  __shared__ unsigned short hpS[16 * 2048];   // 64 KB: 16 tglobs (512 cols) of h' frags
  __shared__ float efS[1024];                 // 4 KB: {E2,F2} for 512 cols
  const int t = threadIdx.x;
  const int kc = blockIdx.x & 15;             // K-chunk (512 cols)
  const int rg = blockIdx.x >> 4;             // row-group (128 rows)

  // stage hptF slice + ef slice (both contiguous)
  {
    const float4* src = reinterpret_cast<const float4*>(hptF + (size_t)kc * 16 * 2048);
    float4* dst = reinterpret_cast<float4*>(hpS);
    #pragma unroll
    for (int i = 0; i < 8; ++i) dst[t + i * 512] = src[t + i * 512];
    if (t < 256)
      reinterpret_cast<float4*>(efS)[t] =
          reinterpret_cast<const float4*>(ef2 + (size_t)kc * 1024)[t];
  }
  __syncthreads();

  const int lane = t & 63;
  const int w = t >> 6;            // wave -> 16-row tile
  const int r15 = lane & 15;       // A-fragment row
  const int kq = lane >> 4;        // k-quad (8 cols)
  const int rowbase = rg * 128 + w * 16;
  const int row = rowbase + r15;

  const float4 rp = rowp[row];
  const float E1 = rp.x, F1 = rp.y, TR = rp.z;

  const int* aP = adj + (size_t)row * NN + kc * 512 + kq * 8;

  f32x4 acc0 = {0.f,0.f,0.f,0.f}, acc1 = acc0, acc2 = acc0, acc3 = acc0;
  float lpart = 0.f;

  // prefetch k-steps 0,1
  int4 c0 = *reinterpret_cast<const int4*>(aP);
  int4 c1 = *reinterpret_cast<const int4*>(aP + 4);
  int4 c2 = *reinterpret_cast<const int4*>(aP + 32);
  int4 c3 = *reinterpret_cast<const int4*>(aP + 36);

  for (int it = 0; it < 7; ++it) {           // 2 k-steps per iter, last pair peeled
    const int* np = aP + (it + 1) * 64;
    const int4 n0 = *reinterpret_cast<const int4*>(np);
    const int4 n1 = *reinterpret_cast<const int4*>(np + 4);
    const int4 n2 = *reinterpret_cast<const int4*>(np + 32);
    const int4 n3 = *reinterpret_cast<const int4*>(np + 36);
    KSBODY(2 * it,     c0, c1)
    KSBODY(2 * it + 1, c2, c3)
    c0 = n0; c1 = n1; c2 = n2; c3 = n3;
  }
  KSBODY(14, c0, c1)
  KSBODY(15, c2, c3)

  // denominator partial: sum k-quads for each row, one atomic per row per wave
  lpart += __shfl_xor(lpart, 16, 64);
  lpart += __shfl_xor(lpart, 32, 64);
  if (lane < 16) atomicAdd(&den[rowbase + r15], lpart);

  // accumulate output partials. C/D: row-in-tile = kq*4 + r, feature = s*16 + r15
  #pragma unroll
  for (int r = 0; r < 4; ++r) {
    float* dstp = &accb[(size_t)(rowbase + kq * 4 + r) * OUTF + r15];
    atomicAdd(dstp,      acc0[r]);
    atomicAdd(dstp + 16, acc1[r]);
    atomicAdd(dstp + 32, acc2[r]);
    atomicAdd(dstp + 48, acc3[r]);
  }
}

// ---------------- Kernel F: out = elu(acc/den)
__global__ __launch_bounds__(256) void k_fin(
    const float* __restrict__ accb, const float* __restrict__ den,
    float* __restrict__ out)
{
  const int i = blockIdx.x * 256 + threadIdx.x;   // 524288
  const float dv = accb[i] / den[i >> 6];
  out[i] = dv > 0.f ? dv : (expf(dv) - 1.f);
}

extern "C" void kernel_launch(void* const* d_in, const int* in_sizes, int n_in,
                              void* d_out, int out_size, void* d_ws, size_t ws_size,
                              hipStream_t stream) {
  (void)in_sizes; (void)n_in; (void)out_size; (void)ws_size;
  const float* X  = (const float*)d_in[0];
  const int* adj  = (const int*)d_in[1];
  const float* W  = (const float*)d_in[2];
  const float* a1 = (const float*)d_in[3];
  const float* a2 = (const float*)d_in[4];
  float* out = (float*)d_out;

  char* ws = (char*)d_ws;
  unsigned short* hptF = (unsigned short*)ws;                    // 1 MB
  float* s1   = (float*)(ws + (size_t)OUTF * NN * 2);            // 32 KB
  float* s2   = s1 + NN;                                         // 32 KB
  float* pmax = s2 + NN;                                         // 1 KB (256 floats)
  float* ef2  = pmax + 256;                                      // 64 KB
  float* rowp = ef2 + 2 * NN;                                    // 128 KB (float4[8192])
  float* accb = rowp + 4 * NN;                                   // 2 MB
  float* den  = accb + (size_t)NN * OUTF;                        // 32 KB

  // zero accumulators (graph-capturable async memset), every call: deterministic
  hipMemsetAsync(accb, 0, ((size_t)NN * OUTF + NN) * sizeof(float), stream);

  hipLaunchKernelGGL(k_prep, dim3(256), dim3(256), 0, stream, X, W, a1, a2, hptF, s1, s2, pmax);
  hipLaunchKernelGGL(k_ef, dim3(NN / 256), dim3(256), 0, stream, s1, s2, pmax, ef2, (float4*)rowp);
  hipLaunchKernelGGL(k_main2, dim3(1024), dim3(512), 0, stream, adj, hptF, ef2, (const float4*)rowp, accb, den);
  hipLaunchKernelGGL(k_fin, dim3(NN * OUTF / 256), dim3(256), 0, stream, accb, den, out);
}

// Round 7
// 80.156 us; speedup vs baseline: 1.7014x; 1.7014x over previous
//
#include <hip/hip_runtime.h>
#include <hip/hip_bf16.h>

#define NN 8192
#define INF_ 256
#define OUTF 64
#define ALPHA 0.2f

typedef __attribute__((ext_vector_type(8))) short short8;
typedef __attribute__((ext_vector_type(4))) float f32x4;

static __device__ __forceinline__ unsigned short f2bf(float f) {
  unsigned u = __builtin_bit_cast(unsigned, f);
  u += 0x7fffu + ((u >> 16) & 1u);          // RNE; inputs are finite
  return (unsigned short)(u >> 16);
}

// ---------------- Kernel A: h' = X@W -> hptF (bf16, MFMA B-fragment order), s1, s2, block s2max
// hptF[((t*4+s)*64 + lane)*8 + j] = h'[t*32 + (lane>>4)*8 + j][s*16 + (lane&15)]
__global__ __launch_bounds__(256) void k_prep(
    const float* __restrict__ X, const float* __restrict__ W,
    const float* __restrict__ a1, const float* __restrict__ a2,
    unsigned short* __restrict__ hptF, float* __restrict__ s1,
    float* __restrict__ s2, float* __restrict__ pmax)
{
  __shared__ float Ws[INF_ * OUTF];   // 64 KB
  __shared__ float Xs[32 * INF_];     // 32 KB
  __shared__ float sm8[8];
  const int t = threadIdx.x;
  const int ib = blockIdx.x;

  #pragma unroll
  for (int i = 0; i < 16; ++i) {
    const int idx = (i * 256 + t) * 4;
    *reinterpret_cast<float4*>(&Ws[idx]) = *reinterpret_cast<const float4*>(&W[idx]);
  }
  const float* Xb = X + (size_t)ib * 32 * INF_;
  #pragma unroll
  for (int i = 0; i < 8; ++i) {
    const int idx = (i * 256 + t) * 4;
    *reinterpret_cast<float4*>(&Xs[idx]) = *reinterpret_cast<const float4*>(&Xb[idx]);
  }
  __syncthreads();

  const int rg = t >> 5;          // 0..7 -> nodes 4*rg..4*rg+3
  const int r0 = rg * 4;
  const int c0 = 2 * (t & 31);    // 2 consecutive output features
  float acc[4][2] = {{0.f,0.f},{0.f,0.f},{0.f,0.f},{0.f,0.f}};

  for (int k = 0; k < INF_; k += 4) {
    float xv[4][4];
    #pragma unroll
    for (int rr = 0; rr < 4; ++rr)
      *reinterpret_cast<float4*>(&xv[rr][0]) =
          *reinterpret_cast<const float4*>(&Xs[(r0 + rr) * INF_ + k]);
    #pragma unroll
    for (int kk = 0; kk < 4; ++kk) {
      const float2 wv = *reinterpret_cast<const float2*>(&Ws[(k + kk) * OUTF + c0]);
      #pragma unroll
      for (int rr = 0; rr < 4; ++rr) {
        acc[rr][0] = fmaf(xv[rr][kk], wv.x, acc[rr][0]);
        acc[rr][1] = fmaf(xv[rr][kk], wv.y, acc[rr][1]);
      }
    }
  }

  const float a10 = a1[c0], a11 = a1[c0 + 1];
  const float a20 = a2[c0], a21 = a2[c0 + 1];
  float sp1[4], sp2[4];
  #pragma unroll
  for (int rr = 0; rr < 4; ++rr) {
    sp1[rr] = acc[rr][0] * a10 + acc[rr][1] * a11;
    sp2[rr] = acc[rr][0] * a20 + acc[rr][1] * a21;
  }
  #pragma unroll
  for (int d = 1; d < 32; d <<= 1) {
    #pragma unroll
    for (int rr = 0; rr < 4; ++rr) {
      sp1[rr] += __shfl_xor(sp1[rr], d, 64);
      sp2[rr] += __shfl_xor(sp2[rr], d, 64);
    }
  }

  // fragment-order store
  const int jj0 = (rg & 1) * 4;
  const int lhi = rg >> 1;
  #pragma unroll
  for (int cc = 0; cc < 2; ++cc) {
    const int feat = c0 + cc;
    const int s = feat >> 4;
    const int ln = lhi * 16 + (feat & 15);
    ushort4 pk;
    pk.x = f2bf(acc[0][cc]); pk.y = f2bf(acc[1][cc]);
    pk.z = f2bf(acc[2][cc]); pk.w = f2bf(acc[3][cc]);
    *reinterpret_cast<ushort4*>(&hptF[(size_t)ib * 2048 + s * 512 + ln * 8 + jj0]) = pk;
  }
  const int gr = ib * 32 + r0;
  if ((t & 31) == 0) {
    #pragma unroll
    for (int rr = 0; rr < 4; ++rr) { s1[gr + rr] = sp1[rr]; s2[gr + rr] = sp2[rr]; }
    sm8[rg] = fmaxf(fmaxf(sp2[0], sp2[1]), fmaxf(sp2[2], sp2[3]));
  }
  __syncthreads();
  if (t == 0) {
    float m = sm8[0];
    #pragma unroll
    for (int i = 1; i < 8; ++i) m = fmaxf(m, sm8[i]);
    pmax[ib] = m;
  }
}

// ---------------- Kernel E: global s2-max + factor tables.
// exp(lrelu(s1_i+s2_j) - m_i) == (E2_j >= TR_i i.e. s1_i+s2_j>=0) ? E1_i*E2_j : F1_i*F2_j.
__global__ __launch_bounds__(256) void k_ef(
    const float* __restrict__ s1, const float* __restrict__ s2,
    const float* __restrict__ pmax, float* __restrict__ ef2, float4* __restrict__ rowp)
{
  __shared__ float smx[4];
  const int t = threadIdx.x;
  float m = pmax[t];
  #pragma unroll
  for (int d = 1; d < 64; d <<= 1) m = fmaxf(m, __shfl_xor(m, d, 64));
  if ((t & 63) == 0) smx[t >> 6] = m;
  __syncthreads();
  const float S2M = fmaxf(fmaxf(smx[0], smx[1]), fmaxf(smx[2], smx[3]));

  const int i = blockIdx.x * 256 + t;      // 8192
  const float d = s2[i] - S2M;
  ef2[2 * i]     = expf(d);                // E2 <= 1
  ef2[2 * i + 1] = expf(ALPHA * d);        // F2 <= 1
  const float y = s1[i] + S2M;             // m_i = lrelu(y)
  const float e1 = y >= 0.f ? 1.f : expf((1.f - ALPHA) * y);
  const float f1 = y >= 0.f ? expf(-(1.f - ALPHA) * y) : 1.f;
  const float tr = expf(-y);               // E2_j >= TR_i  <=>  s1_i+s2_j >= 0
  rowp[i] = make_float4(e1, f1, tr, 0.f);
}

// P-compute + 4 MFMAs from LDS-staged b/ef (shared by all KS* users)
#define PBODY(EPTR, BPTR, A4, B4)                                                \
    const short8 b0 = *reinterpret_cast<const short8*>(BPTR);                    \
    const short8 b1 = *reinterpret_cast<const short8*>((BPTR) + 512);            \
    const short8 b2 = *reinterpret_cast<const short8*>((BPTR) + 1024);           \
    const short8 b3 = *reinterpret_cast<const short8*>((BPTR) + 1536);           \
    const float4 eA = *reinterpret_cast<const float4*>(EPTR);                    \
    const float4 eB = *reinterpret_cast<const float4*>((EPTR) + 4);              \
    const float4 eC = *reinterpret_cast<const float4*>((EPTR) + 8);              \
    const float4 eD = *reinterpret_cast<const float4*>((EPTR) + 12);             \
    const float p0 = ((A4).x > 0) ? ((eA.x >= TR) ? E1 * eA.x : F1 * eA.y) : 0.f;\
    const float p1 = ((A4).y > 0) ? ((eA.z >= TR) ? E1 * eA.z : F1 * eA.w) : 0.f;\
    const float p2 = ((A4).z > 0) ? ((eB.x >= TR) ? E1 * eB.x : F1 * eB.y) : 0.f;\
    const float p3 = ((A4).w > 0) ? ((eB.z >= TR) ? E1 * eB.z : F1 * eB.w) : 0.f;\
    const float p4 = ((B4).x > 0) ? ((eC.x >= TR) ? E1 * eC.x : F1 * eC.y) : 0.f;\
    const float p5 = ((B4).y > 0) ? ((eC.z >= TR) ? E1 * eC.z : F1 * eC.w) : 0.f;\
    const float p6 = ((B4).z > 0) ? ((eD.x >= TR) ? E1 * eD.x : F1 * eD.y) : 0.f;\
    const float p7 = ((B4).w > 0) ? ((eD.z >= TR) ? E1 * eD.z : F1 * eD.w) : 0.f;\
    lpart += ((p0 + p1) + (p2 + p3)) + ((p4 + p5) + (p6 + p7));                  \
    unsigned q0, q1, q2, q3;                                                     \
    asm("v_cvt_pk_bf16_f32 %0, %1, %2" : "=v"(q0) : "v"(p0), "v"(p1));           \
    asm("v_cvt_pk_bf16_f32 %0, %1, %2" : "=v"(q1) : "v"(p2), "v"(p3));           \
    asm("v_cvt_pk_bf16_f32 %0, %1, %2" : "=v"(q2) : "v"(p4), "v"(p5));           \
    asm("v_cvt_pk_bf16_f32 %0, %1, %2" : "=v"(q3) : "v"(p6), "v"(p7));           \
    union { unsigned u[4]; short8 s8; } cv;                                      \
    cv.u[0] = q0; cv.u[1] = q1; cv.u[2] = q2; cv.u[3] = q3;                      \
    const short8 af = cv.s8;                                                     \
    acc0 = __builtin_amdgcn_mfma_f32_16x16x32_bf16(af, b0, acc0, 0, 0, 0);       \
    acc1 = __builtin_amdgcn_mfma_f32_16x16x32_bf16(af, b1, acc1, 0, 0, 0);       \
    acc2 = __builtin_amdgcn_mfma_f32_16x16x32_bf16(af, b2, acc2, 0, 0, 0);       \
    acc3 = __builtin_amdgcn_mfma_f32_16x16x32_bf16(af, b3, acc3, 0, 0, 0);

// LDS-sourced k-step
#define KSL(TLOC, A4, B4)                                                        \
  {                                                                              \
    const unsigned short* bp = &hpS[(TLOC) * 2048 + (lane << 3)];                \
    const float* ep = &efS[(TLOC) * 64 + (kq << 4)];                             \
    PBODY(ep, bp, A4, B4)                                                        \
  }

// ---------------- Kernel C: fused masked-softmax numerator + attn@h' partials.
// 512 blocks = 8 K-chunks(1024 cols) x 64 row-groups(128 rows); 512 thr = 8 waves x 16 rows.
// h' fragments (128 KB) + ef table (8 KB) staged to LDS once -> in-loop VMEM is ONLY the
// adj stream (vmcnt pure adj; b/ef on lgkmcnt; zero in-loop L2 line-requests for b/ef).
// Depth-2-iteration adj register prefetch (~1000 cyc hiding vs ~900 cyc HBM latency).
// Exact-once f32 partial writes (no atomics, no zeroing, deterministic).
__global__ __launch_bounds__(512, 2) void k_main4(
    const int* __restrict__ adj, const unsigned short* __restrict__ hptF,
    const float* __restrict__ ef2, const float4* __restrict__ rowp,
    float* __restrict__ pacc, float* __restrict__ pden)
{
  __shared__ unsigned short hpS[32 * 2048];  // 128 KB: 32 k-steps of b-fragments
  __shared__ float efS[2048];                // 8 KB: {E2,F2} for 1024 cols
  const int t = threadIdx.x;
  const int c = blockIdx.x & 7;              // K-chunk
  const int g = blockIdx.x >> 3;             // row-group

  {
    const float4* src = reinterpret_cast<const float4*>(hptF + (size_t)c * 65536);
    float4* dst = reinterpret_cast<float4*>(hpS);
    #pragma unroll
    for (int i = 0; i < 16; ++i) dst[t + i * 512] = src[t + i * 512];
    reinterpret_cast<float4*>(efS)[t] =
        reinterpret_cast<const float4*>(ef2 + (size_t)c * 2048)[t];
  }
  __syncthreads();

  const int lane = t & 63;
  const int w = t >> 6;
  const int r15 = lane & 15;       // A-fragment row
  const int kq = lane >> 4;        // k-quad (8 cols)
  const int rowbase = g * 128 + w * 16;
  const int row = rowbase + r15;

  const float4 rp = rowp[row];
  const float E1 = rp.x, F1 = rp.y, TR = rp.z;
  const int* aP = adj + (size_t)row * NN + c * 1024 + kq * 8;

  f32x4 acc0 = {0.f,0.f,0.f,0.f}, acc1 = acc0, acc2 = acc0, acc3 = acc0;
  float lpart = 0.f;

  // preload adj for iterations 0 and 1 (2 k-steps each)
  int4 c00 = *reinterpret_cast<const int4*>(aP);
  int4 c01 = *reinterpret_cast<const int4*>(aP + 4);
  int4 c10 = *reinterpret_cast<const int4*>(aP + 32);
  int4 c11 = *reinterpret_cast<const int4*>(aP + 36);
  int4 m00 = *reinterpret_cast<const int4*>(aP + 64);
  int4 m01 = *reinterpret_cast<const int4*>(aP + 68);
  int4 m10 = *reinterpret_cast<const int4*>(aP + 96);
  int4 m11 = *reinterpret_cast<const int4*>(aP + 100);

  for (int it = 0; it < 14; ++it) {
    const int* np = aP + (it + 2) * 64;
    const int4 n00 = *reinterpret_cast<const int4*>(np);
    const int4 n01 = *reinterpret_cast<const int4*>(np + 4);
    const int4 n10 = *reinterpret_cast<const int4*>(np + 32);
    const int4 n11 = *reinterpret_cast<const int4*>(np + 36);
    KSL(2 * it,     c00, c01)
    KSL(2 * it + 1, c10, c11)
    c00 = m00; c01 = m01; c10 = m10; c11 = m11;
    m00 = n00; m01 = n01; m10 = n10; m11 = n11;
  }
  KSL(28, c00, c01)
  KSL(29, c10, c11)
  KSL(30, m00, m01)
  KSL(31, m10, m11)

  // denominator partial: sum k-quads per row, exact-once write
  lpart += __shfl_xor(lpart, 16, 64);
  lpart += __shfl_xor(lpart, 32, 64);
  if (lane < 16) pden[(size_t)c * NN + row] = lpart;

  // output partials, exact-once. C/D: row-in-tile = kq*4 + r, feature = s*16 + r15
  const size_t pb = (size_t)(c * 64 + g) * 128 + w * 16;
  #pragma unroll
  for (int r = 0; r < 4; ++r) {
    float* dp = pacc + (pb + kq * 4 + r) * OUTF + r15;
    dp[0]  = acc0[r];
    dp[16] = acc1[r];
    dp[32] = acc2[r];
    dp[48] = acc3[r];
  }
}

// ---------------- Kernel F: reduce 8 K-chunk partials, divide, elu
__global__ __launch_bounds__(256) void k_fin2(
    const float* __restrict__ pacc, const float* __restrict__ pden,
    float* __restrict__ out)
{
  const int i = blockIdx.x * 256 + threadIdx.x;   // 524288
  const int row = i >> 6;
  const int feat = i & 63;
  const int g = row >> 7;
  const int lr = row & 127;
  float den = 0.f, v = 0.f;
  #pragma unroll
  for (int c = 0; c < 8; ++c) {
    den += pden[(size_t)c * NN + row];
    v   += pacc[((size_t)(c * 64 + g) * 128 + lr) * OUTF + feat];
  }
  const float dv = v / den;
  out[i] = dv > 0.f ? dv : (expf(dv) - 1.f);
}

// ---------------- Fallback (small ws): R5's direct-L2 main kernel (93 us path)
__global__ __launch_bounds__(512, 4) void k_main_r5(
    const int* __restrict__ adj, const unsigned short* __restrict__ hptF,
    const float* __restrict__ ef2, const float4* __restrict__ rowp,
    float* __restrict__ out)
{
  __shared__ float red[8][64][17];
  __shared__ float lden[8][16];
  const int t = threadIdx.x;
  const int lane = t & 63;
  const int w = t >> 6;
  const int rt = blockIdx.x;
  const int r15 = lane & 15;
  const int kq = lane >> 4;
  const int row = rt * 16 + r15;

  const float4 rp = rowp[row];
  const float E1 = rp.x, F1 = rp.y, TR = rp.z;
  const int* aP = adj + (size_t)row * NN + w * 1024 + kq * 8;

  f32x4 acc0 = {0.f,0.f,0.f,0.f}, acc1 = acc0, acc2 = acc0, acc3 = acc0;
  float lpart = 0.f;

  int4 c0 = *reinterpret_cast<const int4*>(aP);
  int4 c1 = *reinterpret_cast<const int4*>(aP + 4);
  int4 c2 = *reinterpret_cast<const int4*>(aP + 32);
  int4 c3 = *reinterpret_cast<const int4*>(aP + 36);

  #define KSG(TGL, A4, B4)                                                       \
    {                                                                            \
      const unsigned short* bp = hptF + ((size_t)(TGL) << 11) + (lane << 3);     \
      const float* ep = ef2 + ((TGL) << 6) + (kq << 4);                          \
      PBODY(ep, bp, A4, B4)                                                      \
    }

  for (int it = 0; it < 7; ++it) {
    const int* np = aP + (it + 1) * 64;
    const int4 n0 = *reinterpret_cast<const int4*>(np);
    const int4 n1 = *reinterpret_cast<const int4*>(np + 4);
    const int4 n2 = *reinterpret_cast<const int4*>(np + 32);
    const int4 n3 = *reinterpret_cast<const int4*>(np + 36);
    KSG((w << 5) + 2 * it,     c0, c1)
    KSG((w << 5) + 2 * it + 1, c2, c3)
    c0 = n0; c1 = n1; c2 = n2; c3 = n3;
  }
  KSG((w << 5) + 14, c0, c1)
  KSG((w << 5) + 15, c2, c3)
  #undef KSG

  lpart += __shfl_xor(lpart, 16, 64);
  lpart += __shfl_xor(lpart, 32, 64);
  if (kq == 0) lden[w][r15] = lpart;

  #pragma unroll
  for (int r = 0; r < 4; ++r) {
    red[w][lane][r]      = acc0[r];
    red[w][lane][4 + r]  = acc1[r];
    red[w][lane][8 + r]  = acc2[r];
    red[w][lane][12 + r] = acc3[r];
  }
  __syncthreads();

  const int orow = t >> 5;
  const int oc = t & 31;
  float den = 0.f;
  #pragma unroll
  for (int ww = 0; ww < 8; ++ww) den += lden[ww][orow];
  const float inv = 1.f / den;
  #pragma unroll
  for (int half = 0; half < 2; ++half) {
    const int col = oc + 32 * half;
    const int s = col >> 4, cc = col & 15;
    const int li = (orow >> 2) * 16 + cc;
    const int ri = s * 4 + (orow & 3);
    float v = 0.f;
    #pragma unroll
    for (int ww = 0; ww < 8; ++ww) v += red[ww][li][ri];
    const float dv = v * inv;
    out[(size_t)(rt * 16 + orow) * OUTF + col] = dv > 0.f ? dv : (expf(dv) - 1.f);
  }
}

extern "C" void kernel_launch(void* const* d_in, const int* in_sizes, int n_in,
                              void* d_out, int out_size, void* d_ws, size_t ws_size,
                              hipStream_t stream) {
  (void)in_sizes; (void)n_in; (void)out_size;
  const float* X  = (const float*)d_in[0];
  const int* adj  = (const int*)d_in[1];
  const float* W  = (const float*)d_in[2];
  const float* a1 = (const float*)d_in[3];
  const float* a2 = (const float*)d_in[4];
  float* out = (float*)d_out;

  char* ws = (char*)d_ws;
  unsigned short* hptF = (unsigned short*)ws;                    // 1 MB
  float* s1   = (float*)(ws + (size_t)OUTF * NN * 2);            // 32 KB
  float* s2   = s1 + NN;                                         // 32 KB
  float* pmax = s2 + NN;                                         // 1 KB (256 floats)
  float* ef2  = pmax + 256;                                      // 64 KB
  float* rowp = ef2 + 2 * NN;                                    // 128 KB (float4[8192])
  float* pacc = rowp + 4 * NN;                                   // 16 MB
  float* pden = pacc + (size_t)8 * NN * OUTF;                    // 256 KB

  hipLaunchKernelGGL(k_prep, dim3(256), dim3(256), 0, stream, X, W, a1, a2, hptF, s1, s2, pmax);
  hipLaunchKernelGGL(k_ef, dim3(NN / 256), dim3(256), 0, stream, s1, s2, pmax, ef2, (float4*)rowp);

  if (ws_size >= (size_t)19 * 1024 * 1024) {
    hipLaunchKernelGGL(k_main4, dim3(512), dim3(512), 0, stream,
                       adj, hptF, ef2, (const float4*)rowp, pacc, pden);
    hipLaunchKernelGGL(k_fin2, dim3(NN * OUTF / 256), dim3(256), 0, stream, pacc, pden, out);
  } else {
    hipLaunchKernelGGL(k_main_r5, dim3(512), dim3(512), 0, stream,
                       adj, hptF, ef2, (const float4*)rowp, out);
  }
}